// Round 10
// baseline (567.430 us; speedup 1.0000x reference)
//
#include <hip/hip_runtime.h>
#include <math.h>

// ---------------------------------------------------------------------------
// 3-layer GAT on MI355X — round 10:
//   * GEMM back to LDS+dbuf (round 8), re-geometried for OCCUPANCY:
//     8 waves x (64x32) per 128x128 tile -> acc 32 AGPR (was 64), total regs
//     ~110 < 128 boundary -> 16 waves/CU (was 8, the round-4..9 invariant).
//   * XCD-chunked swizzle kept (FETCH 101->30MB verified).
//   * edge_w / gathers / CSR / casts unchanged from round 8.
// ---------------------------------------------------------------------------

#define LRELU_SLOPE 0.2f
#define MPAD 50048              // 391 * 128, padded row count for GEMM A tiles

typedef __attribute__((ext_vector_type(8))) short short8;
typedef __attribute__((ext_vector_type(4))) float f32x4;

__device__ __forceinline__ float bf2f(unsigned short u) {
    return __uint_as_float(((unsigned int)u) << 16);
}
__device__ __forceinline__ unsigned short f2bf(float f) {
    unsigned int u = __float_as_uint(f);
    unsigned int r = u + 0x7FFFu + ((u >> 16) & 1u);   // RNE
    return (unsigned short)(r >> 16);
}
__device__ __forceinline__ void load16_to_lds(const void* g, void* l) {
    __builtin_amdgcn_global_load_lds(
        (const __attribute__((address_space(1))) void*)g,
        (__attribute__((address_space(3))) void*)l, 16, 0, 0);
}
__device__ __forceinline__ float lrelu(float e) {
    return e > 0.f ? e : LRELU_SLOPE * e;
}

// ---------------- CSR build ----------------

__global__ void count_deg_kernel(const int* __restrict__ dst, int* __restrict__ counts, int E) {
    int e = blockIdx.x * blockDim.x + threadIdx.x;
    if (e < E) atomicAdd(&counts[dst[e]], 1);
}

__global__ __launch_bounds__(1024) void scan1_kernel(const int* __restrict__ counts,
                                                     int* __restrict__ row_ptr,
                                                     int* __restrict__ partial, int n) {
    __shared__ int wsum[16];
    const int t = threadIdx.x;
    const int lane = t & 63, w = t >> 6;
    const int i = blockIdx.x * 1024 + t;
    int v = (i < n) ? counts[i] : 0;
    int s = v;
    #pragma unroll
    for (int off = 1; off < 64; off <<= 1) {
        int u = __shfl_up(s, off);
        if (lane >= off) s += u;
    }
    if (lane == 63) wsum[w] = s;
    __syncthreads();
    if (w == 0 && lane < 16) {
        int tv = wsum[lane];
        #pragma unroll
        for (int off = 1; off < 16; off <<= 1) {
            int u = __shfl_up(tv, off);
            if (lane >= off) tv += u;
        }
        wsum[lane] = tv;
    }
    __syncthreads();
    int incl = s + (w > 0 ? wsum[w - 1] : 0);
    if (i < n) row_ptr[i + 1] = incl;
    if (t == 0) partial[blockIdx.x] = wsum[15];
}

__global__ void scan2_kernel(int* __restrict__ partial, int nb) {
    int lane = threadIdx.x;
    int v = (lane < nb) ? partial[lane] : 0;
    int s = v;
    #pragma unroll
    for (int off = 1; off < 64; off <<= 1) {
        int u = __shfl_up(s, off);
        if (lane >= off) s += u;
    }
    if (lane < nb) partial[lane] = s - v;
}

__global__ __launch_bounds__(1024) void scan3_kernel(int* __restrict__ row_ptr,
                                                     const int* __restrict__ partial, int n) {
    const int i = blockIdx.x * 1024 + threadIdx.x;
    if (i < n) row_ptr[i + 1] += partial[blockIdx.x];
    if (i == 0) row_ptr[0] = 0;
}

__global__ void init_cursor_kernel(const int* __restrict__ row_ptr, int* __restrict__ cursor, int n) {
    int i = blockIdx.x * blockDim.x + threadIdx.x;
    if (i < n) cursor[i] = row_ptr[i];
}

__global__ void fill_csr_kernel(const int* __restrict__ src, const int* __restrict__ dst,
                                int* __restrict__ cursor, int* __restrict__ csr_src,
                                int* __restrict__ csr_dst, int E) {
    int e = blockIdx.x * blockDim.x + threadIdx.x;
    if (e < E) {
        int d = dst[e];
        int pos = atomicAdd(&cursor[d], 1);
        csr_src[pos] = src[e];
        csr_dst[pos] = d;
    }
}

// ---------------- casts ----------------

__global__ void cast_f32_bf16_kernel(const float* __restrict__ in, unsigned short* __restrict__ out,
                                     size_t n) {
    size_t i = (size_t)blockIdx.x * blockDim.x + threadIdx.x;
    if (i < n) out[i] = f2bf(in[i]);
}

__global__ void transpose_cast_kernel(const float* __restrict__ W, unsigned short* __restrict__ Wt,
                                      int K, int Nw) {
    int i = blockIdx.x * blockDim.x + threadIdx.x;
    if (i < K * Nw) {
        int k = i / Nw, nn = i % Nw;
        Wt[(size_t)nn * K + k] = f2bf(W[i]);
    }
}

// ---------------- bf16 MFMA GEMM + fused alpha dots ------------------------
// C[M,N] = A[Mpad,K] @ Bt[N,K]^T.  128x128 tile, 8 waves (2 row x 4 col),
// each wave 64x32 via acc[4][2] frags of 16x16x32 -> 32 AGPR/wave (occupancy
// fix: total regs < 128 boundary -> 16 waves/CU vs previous 8).
// Double-buffered LDS, prefetch-before-compute; 16B-slot XOR swizzle via
// pre-swizzled global source + same XOR on ds_read (rule #21).
// Bijective XCD-chunked blockIdx swizzle (m204).

__global__ __launch_bounds__(512) void gemm_mfma_kernel(
    const unsigned short* __restrict__ A,    // [>=rowTiles*128, K] bf16
    const unsigned short* __restrict__ Bt,   // [N, K] bf16
    unsigned short* __restrict__ C,          // [M, N] bf16
    const float* __restrict__ a_src,         // [H*C]
    const float* __restrict__ a_dst,
    float* __restrict__ als,                 // [M, H] (zeroed)
    float* __restrict__ ald,
    int M, int N, int K, int H)
{
    __shared__ short As[2 * 128 * 32];
    __shared__ short Bs[2 * 128 * 32];
    const int t = threadIdx.x;
    const int w = t >> 6, lane = t & 63;
    const int wr = w >> 2, wc = w & 3;       // 2 x 4 wave grid

    // bijective XCD-chunk swizzle (m204)
    const int nwg = gridDim.x * gridDim.y;
    const int wg  = blockIdx.x + gridDim.x * blockIdx.y;
    const int qch = nwg >> 3, rch = nwg & 7;
    const int xcd = wg & 7, pos = wg >> 3;
    const int lg  = (xcd < rch ? xcd * (qch + 1) : rch * (qch + 1) + (xcd - rch) * qch) + pos;
    const int bx  = lg % gridDim.x;
    const int by  = lg / gridDim.x;

    const int rowBase = by * 128;
    const int colBase = bx * 128;
    const int q = lane >> 4;        // k-slot 0..3
    const int r16 = lane & 15;
    const int qs = (q ^ ((r16 >> 1) & 3)) * 8;   // swizzled K-slot (shorts)

    f32x4 acc[4][2] = {};

    const int sRow = t >> 2;                               // 0..127 staging row
    const int sOff = ((t & 3) ^ ((sRow >> 1) & 3)) * 8;    // pre-swizzled slot

    const int NT = K >> 5;
    auto stage = [&](int kt, int b) {
        const int koff = kt * 32 + sOff;
        const unsigned short* gA = A + (size_t)(rowBase + sRow) * K + koff;
        load16_to_lds(gA, (char*)As + b * 8192 + w * 1024);
        const unsigned short* gB = Bt + (size_t)(colBase + sRow) * K + koff;
        load16_to_lds(gB, (char*)Bs + b * 8192 + w * 1024);
    };

    stage(0, 0);
    __syncthreads();

    for (int kt = 0; kt < NT; ++kt) {
        const int cur = kt & 1;
        if (kt + 1 < NT) stage(kt + 1, cur ^ 1);   // overlaps with MFMA below

        const short* Ab = As + cur * 4096;
        const short* Bb = Bs + cur * 4096;
        short8 af[4], bfr[2];
        #pragma unroll
        for (int m = 0; m < 4; ++m)
            af[m] = *(const short8*)&Ab[(wr * 64 + m * 16 + r16) * 32 + qs];
        #pragma unroll
        for (int n = 0; n < 2; ++n)
            bfr[n] = *(const short8*)&Bb[(wc * 32 + n * 16 + r16) * 32 + qs];
        #pragma unroll
        for (int m = 0; m < 4; ++m)
            #pragma unroll
            for (int n = 0; n < 2; ++n)
                acc[m][n] = __builtin_amdgcn_mfma_f32_16x16x32_bf16(af[m], bfr[n], acc[m][n], 0, 0, 0);

        __syncthreads();
    }

    float asv[2], adv[2];
    #pragma unroll
    for (int n = 0; n < 2; ++n) {
        int col = colBase + wc * 32 + n * 16 + r16;
        asv[n] = a_src[col];
        adv[n] = a_dst[col];
    }
    const int head = bx;

    #pragma unroll
    for (int m = 0; m < 4; ++m) {
        #pragma unroll
        for (int r = 0; r < 4; ++r) {
            const int gr = rowBase + wr * 64 + m * 16 + q * 4 + r;
            float ps = acc[m][0][r] * asv[0] + acc[m][1][r] * asv[1];
            float pd = acc[m][0][r] * adv[0] + acc[m][1][r] * adv[1];
            #pragma unroll
            for (int off = 8; off >= 1; off >>= 1) {
                ps += __shfl_xor(ps, off);
                pd += __shfl_xor(pd, off);
            }
            if (gr < M) {
                if (r16 == 0) {
                    atomicAdd(&als[(size_t)gr * H + head], ps);
                    atomicAdd(&ald[(size_t)gr * H + head], pd);
                }
                #pragma unroll
                for (int n = 0; n < 2; ++n)
                    C[(size_t)gr * N + colBase + wc * 32 + n * 16 + r16] = f2bf(acc[m][n][r]);
            }
        }
    }
}

// ---------------- edge-parallel weight precompute (atomic-free) ------------

template <int H>
__global__ __launch_bounds__(256) void edge_w_kernel(
    const int* __restrict__ csr_src, const int* __restrict__ csr_dst,
    const float* __restrict__ als, const float* __restrict__ ald,
    float* __restrict__ wplane, int E)
{
    int p = blockIdx.x * 256 + threadIdx.x;
    if (p >= E) return;
    int s = csr_src[p], d = csr_dst[p];
    if constexpr (H == 4) {
        float4 a = *(const float4*)&als[(size_t)s * 4];
        float4 b = *(const float4*)&ald[(size_t)d * 4];
        wplane[p]               = __expf(lrelu(a.x + b.x));
        wplane[(size_t)E + p]   = __expf(lrelu(a.y + b.y));
        wplane[2*(size_t)E + p] = __expf(lrelu(a.z + b.z));
        wplane[3*(size_t)E + p] = __expf(lrelu(a.w + b.w));
    } else {
        wplane[p] = __expf(lrelu(als[s] + ald[d]));
    }
}

// ---------------- gather (H=4): one wave per node ---------------------------

__global__ __launch_bounds__(256) void gather4_kernel(
    const unsigned short* __restrict__ hfeat,   // [N, 512] bf16
    const float* __restrict__ wplane,           // [4][E]
    const int* __restrict__ row_ptr, const int* __restrict__ csr_src,
    const float* __restrict__ bias, unsigned short* __restrict__ out,
    int E, int n_nodes)
{
    const int lane = threadIdx.x & 63;
    const int wv = threadIdx.x >> 6;
    const int n = blockIdx.x * 4 + wv;
    if (n >= n_nodes) return;
    const int head = lane >> 4;
    const int li = lane & 15;
    const int grpBase = lane & ~15;

    const int start = row_ptr[n];
    const int deg = row_ptr[n + 1] - start;
    const float* wpl = wplane + (size_t)head * E;

    float acc[8] = {};
    float wsum = 0.f;
    for (int base = 0; base < deg; base += 16) {
        const int cnt = min(16, deg - base);
        int s_l = 0; float w_l = 0.f;
        if (li < cnt) {
            s_l = csr_src[start + base + li];
            w_l = wpl[start + base + li];
            wsum += w_l;
        }
        for (int e = 0; e < cnt; ++e) {
            const int s = __shfl(s_l, grpBase + e);
            const float a = __shfl(w_l, grpBase + e);
            short8 v = *(const short8*)(hfeat + (size_t)s * 512 + lane * 8);
            #pragma unroll
            for (int j = 0; j < 8; ++j) acc[j] += a * bf2f((unsigned short)v[j]);
        }
    }

    #pragma unroll
    for (int off = 8; off >= 1; off >>= 1) wsum += __shfl_xor(wsum, off);
    const float sc = (deg > 0) ? 1.f / wsum : 0.f;

    float ov[8];
    #pragma unroll
    for (int j = 0; j < 8; ++j) {
        float o = acc[j] * sc + bias[lane * 8 + j];
        ov[j] = o > 0.f ? o : expm1f(o);
    }
    short8 v;
    #pragma unroll
    for (int j = 0; j < 8; ++j) v[j] = (short)f2bf(ov[j]);
    *(short8*)&out[(size_t)n * 512 + lane * 8] = v;
}

// ---------------- gather (H=1, C=128): quarter-wave per edge ----------------

__global__ __launch_bounds__(256) void gather1_kernel(
    const unsigned short* __restrict__ hfeat,   // [N, 128] bf16
    const float* __restrict__ wplane,           // [E]
    const int* __restrict__ row_ptr, const int* __restrict__ csr_src,
    const float* __restrict__ bias, float* __restrict__ out, int n_nodes)
{
    const int lane = threadIdx.x & 63;
    const int wv = threadIdx.x >> 6;
    const int n = blockIdx.x * 4 + wv;
    if (n >= n_nodes) return;
    const int qid = lane >> 4;       // quarter 0..3 = edge slot
    const int ql = lane & 15;        // 16B slot within row

    const int start = row_ptr[n];
    const int deg = row_ptr[n + 1] - start;

    float acc[8] = {};
    float wsum = 0.f;
    for (int base = 0; base < deg; base += 64) {
        const int cnt = min(64, deg - base);
        int s_l = 0; float w_l = 0.f;
        if (lane < cnt) {
            s_l = csr_src[start + base + lane];
            w_l = wplane[start + base + lane];
            wsum += w_l;
        }
        for (int e = 0; e < cnt; e += 4) {
            const int idx = e + qid;
            const int idxc = idx < cnt ? idx : 0;
            const int s = __shfl(s_l, idxc);
            const float aw = __shfl(w_l, idxc);
            const float a = idx < cnt ? aw : 0.f;
            short8 v = *(const short8*)(hfeat + (size_t)s * 128 + ql * 8);
            #pragma unroll
            for (int j = 0; j < 8; ++j) acc[j] += a * bf2f((unsigned short)v[j]);
        }
    }

    #pragma unroll
    for (int off = 32; off >= 1; off >>= 1) wsum += __shfl_xor(wsum, off);
    const float sc = (deg > 0) ? 1.f / wsum : 0.f;

    #pragma unroll
    for (int j = 0; j < 8; ++j) {
        acc[j] += __shfl_xor(acc[j], 16);
        acc[j] += __shfl_xor(acc[j], 32);
    }

    if (qid == 0) {
        float tmp[8];
        #pragma unroll
        for (int j = 0; j < 8; ++j) {
            float o = acc[j] * sc + bias[ql * 8 + j];
            tmp[j] = o > 0.f ? o : expm1f(o);
        }
        float4 o0 = {tmp[0], tmp[1], tmp[2], tmp[3]};
        float4 o1 = {tmp[4], tmp[5], tmp[6], tmp[7]};
        float* op = out + (size_t)n * 128 + ql * 8;
        *(float4*)op = o0;
        *(float4*)(op + 4) = o1;
    }
}

// ---------------------------------------------------------------------------

extern "C" void kernel_launch(void* const* d_in, const int* in_sizes, int n_in,
                              void* d_out, int out_size, void* d_ws, size_t ws_size,
                              hipStream_t stream) {
    const float* x   = (const float*)d_in[0];
    const int*   ei  = (const int*)d_in[1];
    const float* W1  = (const float*)d_in[2];
    const float* as1 = (const float*)d_in[3];
    const float* ad1 = (const float*)d_in[4];
    const float* b1  = (const float*)d_in[5];
    const float* W2  = (const float*)d_in[6];
    const float* as2 = (const float*)d_in[7];
    const float* ad2 = (const float*)d_in[8];
    const float* b2  = (const float*)d_in[9];
    const float* W3  = (const float*)d_in[10];
    const float* as3 = (const float*)d_in[11];
    const float* ad3 = (const float*)d_in[12];
    const float* b3  = (const float*)d_in[13];

    const int N = in_sizes[0] / 64;      // 50000
    const int E = in_sizes[1] / 2;       // 400000
    const int HC = 512;

    const int* src = ei;
    const int* dst = ei + E;

    size_t off = 0;
    auto carve = [&](size_t bytes) -> void* {
        void* p = (char*)d_ws + off;
        off += (bytes + 255) & ~(size_t)255;
        return p;
    };
    unsigned short* x_bf    = (unsigned short*)carve((size_t)MPAD * 64 * 2);
    unsigned short* feat_bf = (unsigned short*)carve((size_t)MPAD * HC * 2);
    unsigned short* h_bf    = (unsigned short*)carve((size_t)N * HC * 2);
    unsigned short* W1t     = (unsigned short*)carve((size_t)512 * 64 * 2);
    unsigned short* W2t     = (unsigned short*)carve((size_t)512 * 512 * 2);
    unsigned short* W3t     = (unsigned short*)carve((size_t)128 * 512 * 2);
    float* stats  = (float*)carve((size_t)N * 8 * sizeof(float));   // als|ald
    float* als    = stats;
    float* ald    = stats + (size_t)N * 4;
    float* wplane = (float*)carve((size_t)4 * E * sizeof(float));
    int*   counts = (int*)carve((size_t)N * sizeof(int));
    int*   row_ptr= (int*)carve((size_t)(N + 1) * sizeof(int));
    int*   cursor = (int*)carve((size_t)N * sizeof(int));
    int*   csr_src= (int*)carve((size_t)E * sizeof(int));
    int*   csr_dst= (int*)carve((size_t)E * sizeof(int));
    int*   partial= (int*)carve(64 * sizeof(int));
    (void)ws_size;

    const int nb = (N + 1023) / 1024;    // 49 <= 64

    // ---- CSR build ----
    hipMemsetAsync(counts, 0, (size_t)N * sizeof(int), stream);
    count_deg_kernel<<<(E + 255) / 256, 256, 0, stream>>>(dst, counts, E);
    scan1_kernel<<<nb, 1024, 0, stream>>>(counts, row_ptr, partial, N);
    scan2_kernel<<<1, 64, 0, stream>>>(partial, nb);
    scan3_kernel<<<nb, 1024, 0, stream>>>(row_ptr, partial, N);
    init_cursor_kernel<<<(N + 255) / 256, 256, 0, stream>>>(row_ptr, cursor, N);
    fill_csr_kernel<<<(E + 255) / 256, 256, 0, stream>>>(src, dst, cursor, csr_src, csr_dst, E);

    // ---- casts ----
    cast_f32_bf16_kernel<<<((size_t)N * 64 + 255) / 256, 256, 0, stream>>>(x, x_bf, (size_t)N * 64);
    transpose_cast_kernel<<<(64 * 512 + 255) / 256, 256, 0, stream>>>(W1, W1t, 64, 512);
    transpose_cast_kernel<<<(512 * 512 + 255) / 256, 256, 0, stream>>>(W2, W2t, 512, 512);
    transpose_cast_kernel<<<(512 * 128 + 255) / 256, 256, 0, stream>>>(W3, W3t, 512, 128);

    const int rowTiles = (N + 127) / 128;   // 391
    const int aggBlocks = (N + 3) / 4;
    const int edgeBlocks = (E + 255) / 256;
    const size_t statsBytes = (size_t)N * 8 * sizeof(float);

    // ---- layer 1 ----
    hipMemsetAsync(stats, 0, statsBytes, stream);
    gemm_mfma_kernel<<<dim3(4, rowTiles), 512, 0, stream>>>(x_bf, W1t, h_bf, as1, ad1,
                                                            als, ald, N, 512, 64, 4);
    edge_w_kernel<4><<<edgeBlocks, 256, 0, stream>>>(csr_src, csr_dst, als, ald, wplane, E);
    gather4_kernel<<<aggBlocks, 256, 0, stream>>>(h_bf, wplane, row_ptr, csr_src,
                                                  b1, feat_bf, E, N);

    // ---- layer 2 ----
    hipMemsetAsync(stats, 0, statsBytes, stream);
    gemm_mfma_kernel<<<dim3(4, rowTiles), 512, 0, stream>>>(feat_bf, W2t, h_bf, as2, ad2,
                                                            als, ald, N, 512, 512, 4);
    edge_w_kernel<4><<<edgeBlocks, 256, 0, stream>>>(csr_src, csr_dst, als, ald, wplane, E);
    gather4_kernel<<<aggBlocks, 256, 0, stream>>>(h_bf, wplane, row_ptr, csr_src,
                                                  b2, feat_bf, E, N);

    // ---- layer 3 ----
    hipMemsetAsync(stats, 0, statsBytes, stream);
    gemm_mfma_kernel<<<dim3(1, rowTiles), 512, 0, stream>>>(feat_bf, W3t, h_bf, as3, ad3,
                                                            als, ald, N, 128, 512, 1);
    edge_w_kernel<1><<<edgeBlocks, 256, 0, stream>>>(csr_src, csr_dst, als, ald, wplane, E);
    gather1_kernel<<<aggBlocks, 256, 0, stream>>>(h_bf, wplane, row_ptr, csr_src,
                                                  b3, (float*)d_out, N);
}

// Round 11
// 383.190 us; speedup vs baseline: 1.4808x; 1.4808x over previous
//
#include <hip/hip_runtime.h>
#include <math.h>

// ---------------------------------------------------------------------------
// 3-layer GAT on MI355X — round 11:
//   * GEMM epilogue ATOMIC-FREE: als/ald partials reduced across the 2
//     column-waves via LDS, then PLAIN stores (each (row,head) owned by
//     exactly one block).  Rounds 6+10 calibrated global fp32 atomicAdd at
//     ~64-71ns each -> the 800K-atomic epilogue was ~55us of the 86us GEMM.
//   * geometry reverted to round-8 best (4 waves, 256 thr, dbuf, swizzles).
//   * stats memsets dropped (plain stores cover all read elements).
// ---------------------------------------------------------------------------

#define LRELU_SLOPE 0.2f
#define MPAD 50048              // 391 * 128, padded row count for GEMM A tiles

typedef __attribute__((ext_vector_type(8))) short short8;
typedef __attribute__((ext_vector_type(4))) float f32x4;

__device__ __forceinline__ float bf2f(unsigned short u) {
    return __uint_as_float(((unsigned int)u) << 16);
}
__device__ __forceinline__ unsigned short f2bf(float f) {
    unsigned int u = __float_as_uint(f);
    unsigned int r = u + 0x7FFFu + ((u >> 16) & 1u);   // RNE
    return (unsigned short)(r >> 16);
}
__device__ __forceinline__ void load16_to_lds(const void* g, void* l) {
    __builtin_amdgcn_global_load_lds(
        (const __attribute__((address_space(1))) void*)g,
        (__attribute__((address_space(3))) void*)l, 16, 0, 0);
}
__device__ __forceinline__ float lrelu(float e) {
    return e > 0.f ? e : LRELU_SLOPE * e;
}

// ---------------- CSR build ----------------

__global__ void count_deg_kernel(const int* __restrict__ dst, int* __restrict__ counts, int E) {
    int e = blockIdx.x * blockDim.x + threadIdx.x;
    if (e < E) atomicAdd(&counts[dst[e]], 1);
}

__global__ __launch_bounds__(1024) void scan1_kernel(const int* __restrict__ counts,
                                                     int* __restrict__ row_ptr,
                                                     int* __restrict__ partial, int n) {
    __shared__ int wsum[16];
    const int t = threadIdx.x;
    const int lane = t & 63, w = t >> 6;
    const int i = blockIdx.x * 1024 + t;
    int v = (i < n) ? counts[i] : 0;
    int s = v;
    #pragma unroll
    for (int off = 1; off < 64; off <<= 1) {
        int u = __shfl_up(s, off);
        if (lane >= off) s += u;
    }
    if (lane == 63) wsum[w] = s;
    __syncthreads();
    if (w == 0 && lane < 16) {
        int tv = wsum[lane];
        #pragma unroll
        for (int off = 1; off < 16; off <<= 1) {
            int u = __shfl_up(tv, off);
            if (lane >= off) tv += u;
        }
        wsum[lane] = tv;
    }
    __syncthreads();
    int incl = s + (w > 0 ? wsum[w - 1] : 0);
    if (i < n) row_ptr[i + 1] = incl;
    if (t == 0) partial[blockIdx.x] = wsum[15];
}

__global__ void scan2_kernel(int* __restrict__ partial, int nb) {
    int lane = threadIdx.x;
    int v = (lane < nb) ? partial[lane] : 0;
    int s = v;
    #pragma unroll
    for (int off = 1; off < 64; off <<= 1) {
        int u = __shfl_up(s, off);
        if (lane >= off) s += u;
    }
    if (lane < nb) partial[lane] = s - v;
}

__global__ __launch_bounds__(1024) void scan3_kernel(int* __restrict__ row_ptr,
                                                     const int* __restrict__ partial, int n) {
    const int i = blockIdx.x * 1024 + threadIdx.x;
    if (i < n) row_ptr[i + 1] += partial[blockIdx.x];
    if (i == 0) row_ptr[0] = 0;
}

__global__ void init_cursor_kernel(const int* __restrict__ row_ptr, int* __restrict__ cursor, int n) {
    int i = blockIdx.x * blockDim.x + threadIdx.x;
    if (i < n) cursor[i] = row_ptr[i];
}

__global__ void fill_csr_kernel(const int* __restrict__ src, const int* __restrict__ dst,
                                int* __restrict__ cursor, int* __restrict__ csr_src,
                                int* __restrict__ csr_dst, int E) {
    int e = blockIdx.x * blockDim.x + threadIdx.x;
    if (e < E) {
        int d = dst[e];
        int pos = atomicAdd(&cursor[d], 1);
        csr_src[pos] = src[e];
        csr_dst[pos] = d;
    }
}

// ---------------- casts ----------------

__global__ void cast_f32_bf16_kernel(const float* __restrict__ in, unsigned short* __restrict__ out,
                                     size_t n) {
    size_t i = (size_t)blockIdx.x * blockDim.x + threadIdx.x;
    if (i < n) out[i] = f2bf(in[i]);
}

__global__ void transpose_cast_kernel(const float* __restrict__ W, unsigned short* __restrict__ Wt,
                                      int K, int Nw) {
    int i = blockIdx.x * blockDim.x + threadIdx.x;
    if (i < K * Nw) {
        int k = i / Nw, nn = i % Nw;
        Wt[(size_t)nn * K + k] = f2bf(W[i]);
    }
}

// ---------------- bf16 MFMA GEMM + fused alpha dots (atomic-free) ----------
// C[M,N] = A[Mpad,K] @ Bt[N,K]^T.  128x128 tile, BK=32, 4 waves (2x2),
// dbuf LDS, prefetch-before-compute, 16B-slot XOR swizzle (rule #21),
// bijective XCD-chunk swizzle.  Epilogue: per-wave alpha partials -> LDS
// cross-wave (wc) reduce -> plain stores to als/ald (block owns its rows).

__global__ __launch_bounds__(256) void gemm_mfma_kernel(
    const unsigned short* __restrict__ A,    // [>=rowTiles*128, K] bf16
    const unsigned short* __restrict__ Bt,   // [N, K] bf16
    unsigned short* __restrict__ C,          // [M, N] bf16
    const float* __restrict__ a_src,         // [H*C]
    const float* __restrict__ a_dst,
    float* __restrict__ als,                 // [M, H]
    float* __restrict__ ald,
    int M, int N, int K, int H)
{
    __shared__ short As[2 * 128 * 32];
    __shared__ short Bs[2 * 128 * 32];
    const int t = threadIdx.x;
    const int w = t >> 6, lane = t & 63;
    const int wr = w >> 1, wc = w & 1;

    // bijective XCD-chunk swizzle (m204)
    const int nwg = gridDim.x * gridDim.y;
    const int wg  = blockIdx.x + gridDim.x * blockIdx.y;
    const int qch = nwg >> 3, rch = nwg & 7;
    const int xcd = wg & 7, pos = wg >> 3;
    const int lg  = (xcd < rch ? xcd * (qch + 1) : rch * (qch + 1) + (xcd - rch) * qch) + pos;
    const int bx  = lg % gridDim.x;
    const int by  = lg / gridDim.x;

    const int rowBase = by * 128;
    const int colBase = bx * 128;
    const int q = lane >> 4;        // k-slot 0..3
    const int r16 = lane & 15;
    const int qs = (q ^ ((r16 >> 1) & 3)) * 8;   // swizzled K-slot (shorts)

    f32x4 acc[4][4] = {};

    const int sRow = t >> 2;                               // 0..63 staging row
    const int sOff = ((t & 3) ^ ((sRow >> 1) & 3)) * 8;    // pre-swizzled slot

    const int NT = K >> 5;
    auto stage = [&](int kt, int b) {
        const int koff = kt * 32 + sOff;
        #pragma unroll
        for (int rr = 0; rr < 2; ++rr) {
            const unsigned short* gA = A + (size_t)(rowBase + rr * 64 + sRow) * K + koff;
            load16_to_lds(gA, (char*)As + b * 8192 + rr * 4096 + w * 1024);
            const unsigned short* gB = Bt + (size_t)(colBase + rr * 64 + sRow) * K + koff;
            load16_to_lds(gB, (char*)Bs + b * 8192 + rr * 4096 + w * 1024);
        }
    };

    stage(0, 0);
    __syncthreads();

    for (int kt = 0; kt < NT; ++kt) {
        const int cur = kt & 1;
        if (kt + 1 < NT) stage(kt + 1, cur ^ 1);   // overlaps with MFMA below

        const short* Ab = As + cur * 4096;
        const short* Bb = Bs + cur * 4096;
        short8 af[4], bfr[4];
        #pragma unroll
        for (int m = 0; m < 4; ++m)
            af[m] = *(const short8*)&Ab[(wr * 64 + m * 16 + r16) * 32 + qs];
        #pragma unroll
        for (int n = 0; n < 4; ++n)
            bfr[n] = *(const short8*)&Bb[(wc * 64 + n * 16 + r16) * 32 + qs];
        #pragma unroll
        for (int m = 0; m < 4; ++m)
            #pragma unroll
            for (int n = 0; n < 4; ++n)
                acc[m][n] = __builtin_amdgcn_mfma_f32_16x16x32_bf16(af[m], bfr[n], acc[m][n], 0, 0, 0);

        __syncthreads();
    }

    float asv[4], adv[4];
    #pragma unroll
    for (int n = 0; n < 4; ++n) {
        int col = colBase + wc * 64 + n * 16 + r16;
        asv[n] = a_src[col];
        adv[n] = a_dst[col];
    }
    const int head = bx;

    // red layout (floats over As): ps[wc][row] at [wc*128+row], pd at 256+...
    float* red = (float*)As;

    #pragma unroll
    for (int m = 0; m < 4; ++m) {
        #pragma unroll
        for (int r = 0; r < 4; ++r) {
            const int rowl = wr * 64 + m * 16 + q * 4 + r;
            const int gr = rowBase + rowl;
            float ps = 0.f, pd = 0.f;
            #pragma unroll
            for (int n = 0; n < 4; ++n) {
                ps += acc[m][n][r] * asv[n];
                pd += acc[m][n][r] * adv[n];
            }
            #pragma unroll
            for (int off = 8; off >= 1; off >>= 1) {
                ps += __shfl_xor(ps, off);
                pd += __shfl_xor(pd, off);
            }
            if (r16 == 0) {
                red[wc * 128 + rowl] = ps;
                red[256 + wc * 128 + rowl] = pd;
            }
            if (gr < M) {
                #pragma unroll
                for (int n = 0; n < 4; ++n)
                    C[(size_t)gr * N + colBase + wc * 64 + n * 16 + r16] = f2bf(acc[m][n][r]);
            }
        }
    }
    __syncthreads();
    if (t < 128) {
        const int gr = rowBase + t;
        if (gr < M) {
            als[(size_t)gr * H + head] = red[t] + red[128 + t];
            ald[(size_t)gr * H + head] = red[256 + t] + red[384 + t];
        }
    }
}

// ---------------- edge-parallel weight precompute (atomic-free) ------------

template <int H>
__global__ __launch_bounds__(256) void edge_w_kernel(
    const int* __restrict__ csr_src, const int* __restrict__ csr_dst,
    const float* __restrict__ als, const float* __restrict__ ald,
    float* __restrict__ wplane, int E)
{
    int p = blockIdx.x * 256 + threadIdx.x;
    if (p >= E) return;
    int s = csr_src[p], d = csr_dst[p];
    if constexpr (H == 4) {
        float4 a = *(const float4*)&als[(size_t)s * 4];
        float4 b = *(const float4*)&ald[(size_t)d * 4];
        wplane[p]               = __expf(lrelu(a.x + b.x));
        wplane[(size_t)E + p]   = __expf(lrelu(a.y + b.y));
        wplane[2*(size_t)E + p] = __expf(lrelu(a.z + b.z));
        wplane[3*(size_t)E + p] = __expf(lrelu(a.w + b.w));
    } else {
        wplane[p] = __expf(lrelu(als[s] + ald[d]));
    }
}

// ---------------- gather (H=4): one wave per node ---------------------------

__global__ __launch_bounds__(256) void gather4_kernel(
    const unsigned short* __restrict__ hfeat,   // [N, 512] bf16
    const float* __restrict__ wplane,           // [4][E]
    const int* __restrict__ row_ptr, const int* __restrict__ csr_src,
    const float* __restrict__ bias, unsigned short* __restrict__ out,
    int E, int n_nodes)
{
    const int lane = threadIdx.x & 63;
    const int wv = threadIdx.x >> 6;
    const int n = blockIdx.x * 4 + wv;
    if (n >= n_nodes) return;
    const int head = lane >> 4;
    const int li = lane & 15;
    const int grpBase = lane & ~15;

    const int start = row_ptr[n];
    const int deg = row_ptr[n + 1] - start;
    const float* wpl = wplane + (size_t)head * E;

    float acc[8] = {};
    float wsum = 0.f;
    for (int base = 0; base < deg; base += 16) {
        const int cnt = min(16, deg - base);
        int s_l = 0; float w_l = 0.f;
        if (li < cnt) {
            s_l = csr_src[start + base + li];
            w_l = wpl[start + base + li];
            wsum += w_l;
        }
        for (int e = 0; e < cnt; ++e) {
            const int s = __shfl(s_l, grpBase + e);
            const float a = __shfl(w_l, grpBase + e);
            short8 v = *(const short8*)(hfeat + (size_t)s * 512 + lane * 8);
            #pragma unroll
            for (int j = 0; j < 8; ++j) acc[j] += a * bf2f((unsigned short)v[j]);
        }
    }

    #pragma unroll
    for (int off = 8; off >= 1; off >>= 1) wsum += __shfl_xor(wsum, off);
    const float sc = (deg > 0) ? 1.f / wsum : 0.f;

    float ov[8];
    #pragma unroll
    for (int j = 0; j < 8; ++j) {
        float o = acc[j] * sc + bias[lane * 8 + j];
        ov[j] = o > 0.f ? o : expm1f(o);
    }
    short8 v;
    #pragma unroll
    for (int j = 0; j < 8; ++j) v[j] = (short)f2bf(ov[j]);
    *(short8*)&out[(size_t)n * 512 + lane * 8] = v;
}

// ---------------- gather (H=1, C=128): quarter-wave per edge ----------------

__global__ __launch_bounds__(256) void gather1_kernel(
    const unsigned short* __restrict__ hfeat,   // [N, 128] bf16
    const float* __restrict__ wplane,           // [E]
    const int* __restrict__ row_ptr, const int* __restrict__ csr_src,
    const float* __restrict__ bias, float* __restrict__ out, int n_nodes)
{
    const int lane = threadIdx.x & 63;
    const int wv = threadIdx.x >> 6;
    const int n = blockIdx.x * 4 + wv;
    if (n >= n_nodes) return;
    const int qid = lane >> 4;       // quarter 0..3 = edge slot
    const int ql = lane & 15;        // 16B slot within row

    const int start = row_ptr[n];
    const int deg = row_ptr[n + 1] - start;

    float acc[8] = {};
    float wsum = 0.f;
    for (int base = 0; base < deg; base += 64) {
        const int cnt = min(64, deg - base);
        int s_l = 0; float w_l = 0.f;
        if (lane < cnt) {
            s_l = csr_src[start + base + lane];
            w_l = wplane[start + base + lane];
            wsum += w_l;
        }
        for (int e = 0; e < cnt; e += 4) {
            const int idx = e + qid;
            const int idxc = idx < cnt ? idx : 0;
            const int s = __shfl(s_l, idxc);
            const float aw = __shfl(w_l, idxc);
            const float a = idx < cnt ? aw : 0.f;
            short8 v = *(const short8*)(hfeat + (size_t)s * 128 + ql * 8);
            #pragma unroll
            for (int j = 0; j < 8; ++j) acc[j] += a * bf2f((unsigned short)v[j]);
        }
    }

    #pragma unroll
    for (int off = 32; off >= 1; off >>= 1) wsum += __shfl_xor(wsum, off);
    const float sc = (deg > 0) ? 1.f / wsum : 0.f;

    #pragma unroll
    for (int j = 0; j < 8; ++j) {
        acc[j] += __shfl_xor(acc[j], 16);
        acc[j] += __shfl_xor(acc[j], 32);
    }

    if (qid == 0) {
        float tmp[8];
        #pragma unroll
        for (int j = 0; j < 8; ++j) {
            float o = acc[j] * sc + bias[ql * 8 + j];
            tmp[j] = o > 0.f ? o : expm1f(o);
        }
        float4 o0 = {tmp[0], tmp[1], tmp[2], tmp[3]};
        float4 o1 = {tmp[4], tmp[5], tmp[6], tmp[7]};
        float* op = out + (size_t)n * 128 + ql * 8;
        *(float4*)op = o0;
        *(float4*)(op + 4) = o1;
    }
}

// ---------------------------------------------------------------------------

extern "C" void kernel_launch(void* const* d_in, const int* in_sizes, int n_in,
                              void* d_out, int out_size, void* d_ws, size_t ws_size,
                              hipStream_t stream) {
    const float* x   = (const float*)d_in[0];
    const int*   ei  = (const int*)d_in[1];
    const float* W1  = (const float*)d_in[2];
    const float* as1 = (const float*)d_in[3];
    const float* ad1 = (const float*)d_in[4];
    const float* b1  = (const float*)d_in[5];
    const float* W2  = (const float*)d_in[6];
    const float* as2 = (const float*)d_in[7];
    const float* ad2 = (const float*)d_in[8];
    const float* b2  = (const float*)d_in[9];
    const float* W3  = (const float*)d_in[10];
    const float* as3 = (const float*)d_in[11];
    const float* ad3 = (const float*)d_in[12];
    const float* b3  = (const float*)d_in[13];

    const int N = in_sizes[0] / 64;      // 50000
    const int E = in_sizes[1] / 2;       // 400000
    const int HC = 512;

    const int* src = ei;
    const int* dst = ei + E;

    size_t off = 0;
    auto carve = [&](size_t bytes) -> void* {
        void* p = (char*)d_ws + off;
        off += (bytes + 255) & ~(size_t)255;
        return p;
    };
    unsigned short* x_bf    = (unsigned short*)carve((size_t)MPAD * 64 * 2);
    unsigned short* feat_bf = (unsigned short*)carve((size_t)MPAD * HC * 2);
    unsigned short* h_bf    = (unsigned short*)carve((size_t)N * HC * 2);
    unsigned short* W1t     = (unsigned short*)carve((size_t)512 * 64 * 2);
    unsigned short* W2t     = (unsigned short*)carve((size_t)512 * 512 * 2);
    unsigned short* W3t     = (unsigned short*)carve((size_t)128 * 512 * 2);
    float* stats  = (float*)carve((size_t)N * 8 * sizeof(float));   // als|ald
    float* als    = stats;
    float* ald    = stats + (size_t)N * 4;
    float* wplane = (float*)carve((size_t)4 * E * sizeof(float));
    int*   counts = (int*)carve((size_t)N * sizeof(int));
    int*   row_ptr= (int*)carve((size_t)(N + 1) * sizeof(int));
    int*   cursor = (int*)carve((size_t)N * sizeof(int));
    int*   csr_src= (int*)carve((size_t)E * sizeof(int));
    int*   csr_dst= (int*)carve((size_t)E * sizeof(int));
    int*   partial= (int*)carve(64 * sizeof(int));
    (void)ws_size;

    const int nb = (N + 1023) / 1024;    // 49 <= 64

    // ---- CSR build ----
    hipMemsetAsync(counts, 0, (size_t)N * sizeof(int), stream);
    count_deg_kernel<<<(E + 255) / 256, 256, 0, stream>>>(dst, counts, E);
    scan1_kernel<<<nb, 1024, 0, stream>>>(counts, row_ptr, partial, N);
    scan2_kernel<<<1, 64, 0, stream>>>(partial, nb);
    scan3_kernel<<<nb, 1024, 0, stream>>>(row_ptr, partial, N);
    init_cursor_kernel<<<(N + 255) / 256, 256, 0, stream>>>(row_ptr, cursor, N);
    fill_csr_kernel<<<(E + 255) / 256, 256, 0, stream>>>(src, dst, cursor, csr_src, csr_dst, E);

    // ---- casts ----
    cast_f32_bf16_kernel<<<((size_t)N * 64 + 255) / 256, 256, 0, stream>>>(x, x_bf, (size_t)N * 64);
    transpose_cast_kernel<<<(64 * 512 + 255) / 256, 256, 0, stream>>>(W1, W1t, 64, 512);
    transpose_cast_kernel<<<(512 * 512 + 255) / 256, 256, 0, stream>>>(W2, W2t, 512, 512);
    transpose_cast_kernel<<<(512 * 128 + 255) / 256, 256, 0, stream>>>(W3, W3t, 512, 128);

    const int rowTiles = (N + 127) / 128;   // 391
    const int aggBlocks = (N + 3) / 4;
    const int edgeBlocks = (E + 255) / 256;

    // ---- layer 1 ----
    gemm_mfma_kernel<<<dim3(4, rowTiles), 256, 0, stream>>>(x_bf, W1t, h_bf, as1, ad1,
                                                            als, ald, N, 512, 64, 4);
    edge_w_kernel<4><<<edgeBlocks, 256, 0, stream>>>(csr_src, csr_dst, als, ald, wplane, E);
    gather4_kernel<<<aggBlocks, 256, 0, stream>>>(h_bf, wplane, row_ptr, csr_src,
                                                  b1, feat_bf, E, N);

    // ---- layer 2 ----
    gemm_mfma_kernel<<<dim3(4, rowTiles), 256, 0, stream>>>(feat_bf, W2t, h_bf, as2, ad2,
                                                            als, ald, N, 512, 512, 4);
    edge_w_kernel<4><<<edgeBlocks, 256, 0, stream>>>(csr_src, csr_dst, als, ald, wplane, E);
    gather4_kernel<<<aggBlocks, 256, 0, stream>>>(h_bf, wplane, row_ptr, csr_src,
                                                  b2, feat_bf, E, N);

    // ---- layer 3 ----
    gemm_mfma_kernel<<<dim3(1, rowTiles), 256, 0, stream>>>(feat_bf, W3t, h_bf, as3, ad3,
                                                            als, ald, N, 128, 512, 1);
    edge_w_kernel<1><<<edgeBlocks, 256, 0, stream>>>(csr_src, csr_dst, als, ald, wplane, E);
    gather1_kernel<<<aggBlocks, 256, 0, stream>>>(h_bf, wplane, row_ptr, csr_src,
                                                  b3, (float*)d_out, N);
}